// Round 1
// 181.018 us; speedup vs baseline: 1.0524x; 1.0524x over previous
//
#include <hip/hip_runtime.h>

typedef __bf16 bf16;
typedef __attribute__((ext_vector_type(8))) __bf16 bf16x8;
typedef __attribute__((ext_vector_type(4))) __bf16 bf16x4;
typedef __attribute__((ext_vector_type(4))) float f32x4;

__device__ __forceinline__ void gload16(const void* g, void* l) {
  __builtin_amdgcn_global_load_lds(
      (__attribute__((address_space(1))) void*)(g),
      (__attribute__((address_space(3))) void*)(l), 16, 0, 0);
}

// ---------------------------------------------------------------------------
// Workspace layout (bytes):
//   xh  : NHWC padded input, bf16 [130][130][512]        = 17,305,600
//   w1t : conv1 weights,     bf16 [9][512 oc][512 c]     =  4,718,592
//   w2p : packed head wts,   bf16 [80 oc2][512 c]        =     81,920
//   mid : conv1 output NHWC, bf16 [16384 px][512 oc]     = 16,777,216
// ---------------------------------------------------------------------------
#define WS_XH   0
#define WS_W1T  17305600
#define WS_W2P  22024192
#define WS_MID  22106112

#define OUT_CLS 786432
#define OUT_ROI 1179648

// ---------------- fused prep: border | w1 repack | w2 pack | transpose -----
// grid = 132 + 1024 + 160 + 2048 = 3364 blocks, 256 thr    (unchanged)
__global__ void prep_all(int4* __restrict__ xh4,
                         const float* __restrict__ w1, bf16* __restrict__ w1t,
                         const float* __restrict__ loc_w,
                         const float* __restrict__ score_w,
                         bf16* __restrict__ w2p,
                         const float* __restrict__ x, bf16* __restrict__ xh) {
  __shared__ float lds[64][65];
  float* ldsf = &lds[0][0];
  const int t = threadIdx.x;
  const int b = blockIdx.x;
  if (b < 132) {                       // ---- xh halo border zeroing
    const int4 z = make_int4(0, 0, 0, 0);
    if (b < 130) {
      if (t < 64)       xh4[(b * 130 + 0) * 64 + t] = z;
      else if (t < 128) xh4[(b * 130 + 129) * 64 + (t - 64)] = z;
    } else {
      const int r = (b == 130) ? 0 : 129;
      for (int i = t; i < 8320; i += 256) xh4[r * 8320 + i] = z;
    }
  } else if (b < 1156) {               // ---- w1 [oc][c][3][3] -> w1t[j][oc][c]
    const int bb = b - 132;
    const long base = (long)bb * 2304;
#pragma unroll
    for (int i = 0; i < 9; ++i) ldsf[i * 256 + t] = w1[base + i * 256 + t];
    __syncthreads();
    const int pair0 = bb * 256;        // pair = oc*512 + c
#pragma unroll
    for (int j = 0; j < 9; ++j)
      w1t[(long)j * 262144 + pair0 + t] = (bf16)ldsf[t * 9 + j];
  } else if (b < 1316) {               // ---- pack loc_w+score_w -> w2p[80][512]
    const int idx = (b - 1156) * 256 + t;
    const int c  = idx & 511;
    const int oc = idx >> 9;
    float v = 0.f;
    if (oc < 48)      v = loc_w[oc * 512 + c];
    else if (oc < 72) v = score_w[(oc - 48) * 512 + c];
    w2p[idx] = (bf16)v;
  } else {                             // ---- NCHW fp32 -> NHWC bf16 transpose
    const int bb   = b - 1316;
    const int ct   = bb & 7;
    const int colt = (bb >> 3) & 1;
    const int r    = 1 + (bb >> 4);
    const int c0   = ct * 64;
    const int col0 = 1 + colt * 64;
    const int lcol = t & 63;
    const int coff = t >> 6;
#pragma unroll
    for (int i = 0; i < 16; ++i) {
      const int cl = coff + i * 4;
      lds[cl][lcol] = x[(long)(c0 + cl) * 16384 + (r - 1) * 128 + (col0 - 1) + lcol];
    }
    __syncthreads();
#pragma unroll
    for (int i = 0; i < 2; ++i) {
      const int idx = i * 256 + t;
      const int pxl = idx >> 3;
      const int oct = idx & 7;
      bf16x8 v;
#pragma unroll
      for (int e = 0; e < 8; ++e) v[e] = (bf16)lds[oct * 8 + e][pxl];
      *(bf16x8*)(xh + (long)(r * 130 + col0 + pxl) * 512 + c0 + oct * 8) = v;
    }
  }
}

// ---------------- conv1 implicit GEMM: supply-traffic redesign -------------
// Previous version (512 blk, 128x128 tile, per-tap B staging) was bound by
// L2-miss/L3 supply: 1.18 GB staged @ ~12.4 TB/s -> 95us, MfmaUtil 34%.
// Redundancy removed here:
//   A: 64-oc x 512-px (4 image rows) blocks -> w1t re-staged by 32 px-tiles
//      instead of 128 (604->151 MB); ocT = blk%8 pins each oc-slice to one
//      XCD so w1t is L2-resident (L3 A-traffic ~5 MB).
//   B: the 9 conv taps of one K-column share one staged xh row-window
//      (784 rows x 64B) instead of 9 shifted copies (604->218 MB).
// Schedule: 16 superslots (ck) x 9 subslots (tap j). Per subslot: 16 MFMA
// per wave. Waves 0-3 stage A(j+2) (ring-4 x 4KB, vmcnt(1) each subslot);
// waves 4-7 stage B(ck+1) (ping-pong 2 x 49KB, spread over subslots 0-5,
// vmcnt(0) once per superslot at j=0). No full vmcnt drain mid-superslot;
// every stage has >=2 subslots (>1500cy) of latency cover. LDS 117KB ->
// 1 block/CU, 8 waves (2/SIMD, same occupancy as before).
// Fragment swizzle identical to the proven one, generalized: stored pos =
// chunk ^ ((row>>1)&3) holds for arbitrary (odd) row bases.
__global__ __launch_bounds__(512, 2) void conv1_gemm(
    const bf16* __restrict__ w1t, const bf16* __restrict__ xh,
    const float* __restrict__ b1, bf16* __restrict__ mid) {
  extern __shared__ char smem[];
  // layout: B ping [784 rows][64B] @ 0 ; B pong @ 50176 ; A ring 4x4KB @ 100352
  char* Bb0 = smem;
  char* Bb1 = smem + 50176;
  char* Ab  = smem + 100352;

  const int tid  = threadIdx.x;
  const int wave = tid >> 6;
  const int lane = tid & 63;
  const int quad = lane >> 4;
  const int l15  = lane & 15;
  const int b    = blockIdx.x;
  const int ocT  = b & 7;          // XCD-affine: same ocT -> same XCD L2
  const int r4   = b >> 3;         // 4-image-row px tile, 0..31
  const long rbase = (long)r4 * 520;        // 4*130 xh rows per tile

  const char* w1tB = (const char*)w1t + (long)ocT * 65536;
  const char* xhB  = (const char*)xh;

  const int srow = lane >> 2;                               // 16 rows/unit
  const int schk = ((lane & 3) ^ ((lane >> 3) & 3)) << 4;   // src chunk swizzle

  // stage 1KB unit of A(tap j, col ck): wave w (0..3) stages rows [w*16,+16)
  auto stageA = [&](int ck, int j, int slot) {
    const char* src = w1tB + (long)j * 524288 +
                      (long)(wave * 16 + srow) * 1024 + ck * 64 + schk;
    gload16(src, Ab + slot * 4096 + wave * 1024);
  };
  // stage 1KB unit u (16 xh rows) of the B window at column ck
  auto stageB = [&](int ck, int u, char* Bt) {
    const char* src = xhB + (rbase + u * 16 + srow) * 1024 + ck * 64 + schk;
    gload16(src, Bt + u * 1024);
  };

  // per-wave B row bases: px p = wave*64 + ni*16 + l15 ->
  // local row = (p>>7)*130 + (p&127) + l15  (+ ky*130 + kx at use)
  const int p0 = wave * 64;
  int rowb[4];
#pragma unroll
  for (int ni = 0; ni < 4; ++ni) {
    const int pb = p0 + ni * 16;
    rowb[ni] = (pb >> 7) * 130 + (pb & 127) + l15;
  }
  const int aoff = l15 * 64 + ((quad ^ ((l15 >> 1) & 3)) << 4);

  f32x4 acc[4][4];
#pragma unroll
  for (int i = 0; i < 4; ++i)
#pragma unroll
    for (int k = 0; k < 4; ++k) acc[i][k] = (f32x4){0.f, 0.f, 0.f, 0.f};

  auto compute = [&](int koff, int slot, const char* Bt) {
    bf16x8 af[4], bfr[4];
#pragma unroll
    for (int mi = 0; mi < 4; ++mi)
      af[mi] = *(const bf16x8*)(Ab + slot * 4096 + mi * 1024 + aoff);
#pragma unroll
    for (int ni = 0; ni < 4; ++ni) {
      const int row = rowb[ni] + koff;
      bfr[ni] = *(const bf16x8*)(Bt + row * 64 + ((quad ^ ((row >> 1) & 3)) << 4));
    }
    __builtin_amdgcn_s_setprio(1);
#pragma unroll
    for (int mi = 0; mi < 4; ++mi)
#pragma unroll
      for (int ni = 0; ni < 4; ++ni)
        acc[mi][ni] = __builtin_amdgcn_mfma_f32_16x16x32_bf16(
            af[mi], bfr[ni], acc[mi][ni], 0, 0, 0);
    __builtin_amdgcn_s_setprio(0);
  };

#define WAITA1 asm volatile("s_waitcnt vmcnt(1)" ::: "memory")
#define WAIT0  asm volatile("s_waitcnt vmcnt(0)" ::: "memory")
#define BARR   __builtin_amdgcn_s_barrier()

  // prologue: B(0) fully; A(0,0), A(0,1) into ring slots 0,1
  if (wave < 4) {
    stageA(0, 0, 0);
    stageA(0, 1, 1);
  } else {
    const int u0 = (wave == 4) ? 0 : 13 + (wave - 5) * 12;
    const int n  = (wave == 4) ? 13 : 12;
    for (int u = 0; u < n; ++u) stageB(0, u0 + u, Bb0);
  }

  for (int s = 0; s < 15; ++s) {
    char* Bcur = (s & 1) ? Bb1 : Bb0;
    char* Bnxt = (s & 1) ? Bb0 : Bb1;
#pragma unroll
    for (int j = 0; j < 9; ++j) {
      if (wave < 4) { WAITA1; }
      else if (j == 0) { WAIT0; }
      BARR;
      if (wave < 4) {                      // A staging: 2 subslots ahead
        if (j < 7) stageA(s, j + 2, (s + j + 2) & 3);
        else       stageA(s + 1, j - 7, (s + j + 2) & 3);
      } else if (j < 6) {                  // B(ck+1): ~2 units/subslot
        int u0, n;
        if (wave == 4) { n = (j == 0) ? 3 : 2; u0 = (j == 0) ? 0 : 3 + (j - 1) * 2; }
        else           { n = 2; u0 = 13 + (wave - 5) * 12 + j * 2; }
        for (int u = 0; u < n; ++u) stageB(s + 1, u0 + u, Bnxt);
      }
      compute((j / 3) * 130 + (j % 3), (s + j) & 3, Bcur);
    }
  }
  { // s = 15 peel: no next-superslot staging; exact drain counts
    const int s = 15;
    char* Bcur = Bb1;
#pragma unroll
    for (int j = 0; j < 9; ++j) {
      if (wave < 4) { if (j < 8) { WAITA1; } else { WAIT0; } }
      else if (j == 0) { WAIT0; }
      BARR;
      if (wave < 4 && j < 7) stageA(s, j + 2, (s + j + 2) & 3);
      compute((j / 3) * 130 + (j % 3), (s + j) & 3, Bcur);
    }
  }

#undef WAITA1
#undef WAIT0
#undef BARR

  // epilogue: bias + relu, store bf16 NHWC mid[px][oc]
#pragma unroll
  for (int mi = 0; mi < 4; ++mi) {
    const int oc = ocT * 64 + mi * 16 + quad * 4;
    const float bv0 = b1[oc], bv1 = b1[oc + 1], bv2 = b1[oc + 2], bv3 = b1[oc + 3];
#pragma unroll
    for (int ni = 0; ni < 4; ++ni) {
      const int pb  = p0 + ni * 16;
      const int gpx = (r4 * 4 + (pb >> 7)) * 128 + (pb & 127) + l15;
      f32x4 a = acc[mi][ni];
      float t0 = a[0] + bv0; t0 = t0 > 0.f ? t0 : 0.f;
      float t1 = a[1] + bv1; t1 = t1 > 0.f ? t1 : 0.f;
      float t2 = a[2] + bv2; t2 = t2 > 0.f ? t2 : 0.f;
      float t3 = a[3] + bv3; t3 = t3 > 0.f ? t3 : 0.f;
      bf16x4 v = {(bf16)t0, (bf16)t1, (bf16)t2, (bf16)t3};
      *(bf16x4*)(mid + (long)gpx * 512 + oc) = v;
    }
  }
}

// ---------------- head: barrier-free K-split GEMM + anchor decode ----------
__global__ __launch_bounds__(256) void head_gemm(
    const bf16* __restrict__ w2p, const bf16* __restrict__ mid,
    const float* __restrict__ loc_b, const float* __restrict__ score_b,
    float* __restrict__ out) {
  __shared__ f32x4 red[3][64][5];
  const int tid  = threadIdx.x;
  const int wave = tid >> 6;
  const int lane = tid & 63;
  const int quad = lane >> 4;
  const int l15  = lane & 15;
  const int px0  = blockIdx.x * 16;
  const bf16* mB = mid + (long)px0 * 512;

  f32x4 acc[5];
#pragma unroll
  for (int i = 0; i < 5; ++i) acc[i] = (f32x4){0.f, 0.f, 0.f, 0.f};

#pragma unroll
  for (int st = 0; st < 4; ++st) {
    const int k0 = wave * 128 + st * 32;
    bf16x8 bfr = *(const bf16x8*)(mB + (long)l15 * 512 + k0 + quad * 8);
#pragma unroll
    for (int mi = 0; mi < 5; ++mi) {
      bf16x8 af = *(const bf16x8*)(w2p + (long)(mi * 16 + l15) * 512 + k0 + quad * 8);
      acc[mi] = __builtin_amdgcn_mfma_f32_16x16x32_bf16(af, bfr, acc[mi], 0, 0, 0);
    }
  }

  if (wave > 0) {
#pragma unroll
    for (int mi = 0; mi < 5; ++mi) red[wave - 1][lane][mi] = acc[mi];
  }
  __syncthreads();
  if (wave != 0) return;
#pragma unroll
  for (int w = 0; w < 3; ++w)
#pragma unroll
    for (int mi = 0; mi < 5; ++mi) acc[mi] += red[w][lane][mi];

  const int p    = px0 + l15;
  const int hh   = p >> 7;
  const int wcol = p & 127;
  const float cx = 16.f * (float)hh;
  const float cy = 16.f * (float)wcol;
  const float s0 = quad == 0 ? 45.f : quad == 1 ? 91.f : quad == 2 ? 181.f : 362.f;
  const float s1 = quad == 0 ? 32.f : quad == 1 ? 64.f : quad == 2 ? 128.f : 256.f;
  const float s2 = quad == 0 ? 23.f : quad == 1 ? 45.f : quad == 2 ? 91.f : 181.f;
  const float aw[3] = {s0, s1, s2};
  const float ah[3] = {s2, s1, s0};
#pragma unroll
  for (int mi = 0; mi < 5; ++mi) {
#pragma unroll
    for (int r = 0; r < 4; ++r) {
      const int oc2 = mi * 16 + quad * 4 + r;
      float v = acc[mi][r];
      if (mi < 3) {
        v += loc_b[oc2];
        out[p * 48 + oc2] = v;
        float roi;
        if (r == 0)      roi = v * aw[mi] + cx;
        else if (r == 1) roi = v * ah[mi] + cy;
        else if (r == 2) roi = __expf(v) * aw[mi];
        else             roi = __expf(v) * ah[mi];
        out[OUT_ROI + p * 48 + oc2] = roi;
      } else {
        const int sc = oc2 - 48;
        if (sc < 24) {
          v += score_b[sc];
          out[OUT_CLS + p * 24 + sc] = v;
        }
      }
    }
  }
}

// ---------------------------------------------------------------------------
extern "C" void kernel_launch(void* const* d_in, const int* in_sizes, int n_in,
                              void* d_out, int out_size, void* d_ws, size_t ws_size,
                              hipStream_t stream) {
  (void)in_sizes; (void)n_in; (void)out_size; (void)ws_size;
  const float* x       = (const float*)d_in[0];
  const float* conv1_w = (const float*)d_in[1];
  const float* conv1_b = (const float*)d_in[2];
  const float* score_w = (const float*)d_in[3];
  const float* score_b = (const float*)d_in[4];
  const float* loc_w   = (const float*)d_in[5];
  const float* loc_b   = (const float*)d_in[6];
  char* ws = (char*)d_ws;
  bf16* xh  = (bf16*)(ws + WS_XH);
  bf16* w1t = (bf16*)(ws + WS_W1T);
  bf16* w2p = (bf16*)(ws + WS_W2P);
  bf16* mid = (bf16*)(ws + WS_MID);
  float* out = (float*)d_out;

  static int attr_done = 0;
  if (!attr_done) {
    (void)hipFuncSetAttribute((const void*)conv1_gemm,
                              hipFuncAttributeMaxDynamicSharedMemorySize, 116736);
    attr_done = 1;
  }

  hipLaunchKernelGGL(prep_all,   dim3(3364), dim3(256), 0, stream,
                     (int4*)xh, conv1_w, w1t, loc_w, score_w, w2p, x, xh);
  hipLaunchKernelGGL(conv1_gemm, dim3(256),  dim3(512), 116736, stream,
                     w1t, xh, conv1_b, mid);
  hipLaunchKernelGGL(head_gemm,  dim3(1024), dim3(256), 0, stream,
                     w2p, mid, loc_b, score_b, out);
}